// Round 3
// baseline (230.968 us; speedup 1.0000x reference)
//
#include <hip/hip_runtime.h>
#include <stdint.h>

typedef _Float16 half4v __attribute__((ext_vector_type(4)));
typedef _Float16 half8v __attribute__((ext_vector_type(8)));
typedef float    f32x4  __attribute__((ext_vector_type(4)));

#define NB 8
#define SXX 2048
#define DD 512
#define QBLK 32
#define TBLK 64
#define NDT 32                 /* D/16 d-tiles */
#define NITER 32               /* 2048 / TBLK */

/* y tile: row-major fp16, padded rows 520 f16 = 1040 B (row bank-rotate 4). */
#define RSB 1040u
/* merge buffer (reuses y region): 32 rows x 524 f32 = 2096 B rows (2-way max) */
#define MRGS 2096u
#define MLOFF 67072u           /* m/l exchange: 128 f32 = 512 B */
#define LDS_BYTES 67584

__global__ __launch_bounds__(256, 2)
void attn_fused(const float* __restrict__ x, const float* __restrict__ y,
                float* __restrict__ out) {
  extern __shared__ char smem[];
  const int bid   = blockIdx.x;
  const int b     = bid & 7;      /* one batch per XCD -> y batch L2-resident */
  const int qtile = bid >> 3;
  const int tid   = threadIdx.x;
  const int wave  = tid >> 6;
  const int lane  = tid & 63;
  const int l15   = lane & 15;
  const int g     = lane >> 4;
  const int qg    = wave & 1;     /* q-group: 16 rows */
  const int th    = wave >> 1;    /* t-half within each K-tile */

  const float* xb = x + (size_t)b * SXX * DD;
  const float* yb = y + (size_t)b * SXX * DD;
  float* outb     = out + (size_t)b * SXX * (2 * DD);
  const int qbase = qtile * QBLK;

  /* ---- out[:, :512] = x (exact fp32 copy) ---- */
  {
    const f32x4* src = (const f32x4*)(xb + (size_t)qbase * DD);
    for (int i = tid; i < QBLK * (DD / 4); i += 256) {
      f32x4 v = src[i];
      const int row = i >> 7;
      const int c4  = i & 127;
      *(f32x4*)(outb + (size_t)(qbase + row) * (2 * DD) + c4 * 4) = v;
    }
  }

  /* ---- Q fragments (fp16), B-operand of 16x16x32:
     lane holds col q = qbase+16*qg+l15, elems d = 32c + 8g + j ---- */
  const int qrow = qbase + qg * 16 + l15;
  half8v bq[16];
  {
    const float* xr = xb + (size_t)qrow * DD;
#pragma unroll
    for (int c = 0; c < 16; ++c) {
      const int d0 = c * 32 + g * 8;
      f32x4 f0 = *(const f32x4*)(xr + d0);
      f32x4 f1 = *(const f32x4*)(xr + d0 + 4);
      half8v h;
      h[0] = (_Float16)f0[0]; h[1] = (_Float16)f0[1];
      h[2] = (_Float16)f0[2]; h[3] = (_Float16)f0[3];
      h[4] = (_Float16)f1[0]; h[5] = (_Float16)f1[1];
      h[6] = (_Float16)f1[2]; h[7] = (_Float16)f1[3];
      bq[c] = h;
    }
  }

  f32x4 acc[NDT];
#pragma unroll
  for (int i = 0; i < NDT; ++i) acc[i] = (f32x4){0.f, 0.f, 0.f, 0.f};
  float mrun = -3.0e38f;
  float lrun = 0.0f;

  /* ---- stage tile 0 ---- */
  {
    const float* ybt = yb;
#pragma unroll
    for (int kb = 0; kb < 4; ++kb) {
      f32x4 f[8];
#pragma unroll
      for (int k4 = 0; k4 < 4; ++k4) {
        const int u = tid + (kb * 4 + k4) * 256;
        const float* p = ybt + (u >> 6) * DD + (u & 63) * 8;
        f[k4 * 2]     = *(const f32x4*)(p);
        f[k4 * 2 + 1] = *(const f32x4*)(p + 4);
      }
#pragma unroll
      for (int k4 = 0; k4 < 4; ++k4) {
        const int u = tid + (kb * 4 + k4) * 256;
        half8v h;
        h[0]=(_Float16)f[k4*2][0]; h[1]=(_Float16)f[k4*2][1];
        h[2]=(_Float16)f[k4*2][2]; h[3]=(_Float16)f[k4*2][3];
        h[4]=(_Float16)f[k4*2+1][0]; h[5]=(_Float16)f[k4*2+1][1];
        h[6]=(_Float16)f[k4*2+1][2]; h[7]=(_Float16)f[k4*2+1][3];
        *(half8v*)(smem + (uint32_t)(u >> 6) * RSB + (uint32_t)(u & 63) * 16u) = h;
      }
    }
  }
  __syncthreads();

  for (int it = 0; it < NITER; ++it) {
    /* ---- QK^T swapped: S^T = mfma(A=y, B=x) on this wave's 32 t-rows.
       A: lane holds row t = 32*th + 16*tt + l15, elems d = 32c + 8g + j.
       C: lane holds q = l15 (col), t-row = 32*th + 16*tt + 4g + r. ---- */
    f32x4 st[2];
    st[0] = (f32x4){0.f, 0.f, 0.f, 0.f};
    st[1] = (f32x4){0.f, 0.f, 0.f, 0.f};
#pragma unroll
    for (int c = 0; c < 16; ++c) {
      const uint32_t db = 64u * (uint32_t)c + 16u * (uint32_t)g;
#pragma unroll
      for (int tt = 0; tt < 2; ++tt) {
        const half8v af =
            *(const half8v*)(smem + (uint32_t)(th * 32 + tt * 16 + l15) * RSB + db);
        st[tt] = __builtin_amdgcn_mfma_f32_16x16x32_f16(af, bq[c], st[tt], 0, 0, 0);
      }
    }

    /* ---- online softmax over this wave's 32 t's, per q = l15 ---- */
    float tmax = -3.0e38f;
#pragma unroll
    for (int tt = 0; tt < 2; ++tt) {
#pragma unroll
      for (int r = 0; r < 4; ++r) tmax = fmaxf(tmax, st[tt][r]);
    }
    tmax = fmaxf(tmax, __shfl_xor(tmax, 16));
    tmax = fmaxf(tmax, __shfl_xor(tmax, 32));
    const float mnew = fmaxf(mrun, tmax);
    const bool  need = (mnew > mrun);
    float pvv[8];
    float rsum = 0.f;
#pragma unroll
    for (int tt = 0; tt < 2; ++tt) {
#pragma unroll
      for (int r = 0; r < 4; ++r) {
        const float e = __expf(st[tt][r] - mnew);
        pvv[tt * 4 + r] = e;
        rsum += e;
      }
    }
    rsum += __shfl_xor(rsum, 16);
    rsum += __shfl_xor(rsum, 32);
    const float scale = __expf(mrun - mnew);
    lrun = lrun * scale + rsum;
    mrun = mnew;

    if (__any(need)) {
      float rs[4];
#pragma unroll
      for (int r = 0; r < 4; ++r) rs[r] = __shfl(scale, 4 * g + r);
#pragma unroll
      for (int dt = 0; dt < NDT; ++dt) {
        acc[dt][0] *= rs[0]; acc[dt][1] *= rs[1];
        acc[dt][2] *= rs[2]; acc[dt][3] *= rs[3];
      }
    }

    /* ---- P A-fragment (16x16x32, K = this wave's 32 t's), permuted-k
       consistent with the tr-read B-fragment ---- */
    half8v pa8;
#pragma unroll
    for (int j = 0; j < 8; ++j) pa8[j] = (_Float16)pvv[j];

    /* ---- PV: V B-fragments via positional tr-read (2 per d-tile),
       2-ahead pipelined with counted lgkmcnt ---- */
    {
      const uint32_t rb = (uint32_t)(th * 32 + 4 * g + (l15 >> 2)) * RSB +
                          (uint32_t)(l15 & 3) * 8u;
      half4v trv[3][2];
#pragma unroll
      for (int dt = 0; dt < NDT + 2; ++dt) {
        if (dt < NDT) {
          const uint32_t a = rb + (uint32_t)dt * 32u;
          const int s = dt % 3;
          asm volatile("ds_read_b64_tr_b16 %0, %1" : "=v"(trv[s][0]) : "v"(a));
          asm volatile("ds_read_b64_tr_b16 %0, %1" : "=v"(trv[s][1]) : "v"(a + 16u * RSB));
        }
        if (dt >= 2) {
          if (dt < NDT) {
            asm volatile("s_waitcnt lgkmcnt(4)" ::: "memory");
          } else if (dt == NDT) {
            asm volatile("s_waitcnt lgkmcnt(2)" ::: "memory");
          } else {
            asm volatile("s_waitcnt lgkmcnt(0)" ::: "memory");
          }
          __builtin_amdgcn_sched_barrier(0);
          const int dd = dt - 2;
          const int s = dd % 3;
          const half8v b8 = __builtin_shufflevector(trv[s][0], trv[s][1],
                                                    0, 1, 2, 3, 4, 5, 6, 7);
          acc[dd] = __builtin_amdgcn_mfma_f32_16x16x32_f16(pa8, b8, acc[dd], 0, 0, 0);
        }
      }
    }
    __syncthreads();

    /* ---- stage tile it+1 (single buffer; all reads above are done) ---- */
    if (it + 1 < NITER) {
      const float* ybt = yb + (size_t)(it + 1) * TBLK * DD;
#pragma unroll
      for (int kb = 0; kb < 4; ++kb) {
        f32x4 f[8];
#pragma unroll
        for (int k4 = 0; k4 < 4; ++k4) {
          const int u = tid + (kb * 4 + k4) * 256;
          const float* p = ybt + (u >> 6) * DD + (u & 63) * 8;
          f[k4 * 2]     = *(const f32x4*)(p);
          f[k4 * 2 + 1] = *(const f32x4*)(p + 4);
        }
#pragma unroll
        for (int k4 = 0; k4 < 4; ++k4) {
          const int u = tid + (kb * 4 + k4) * 256;
          half8v h;
          h[0]=(_Float16)f[k4*2][0]; h[1]=(_Float16)f[k4*2][1];
          h[2]=(_Float16)f[k4*2][2]; h[3]=(_Float16)f[k4*2][3];
          h[4]=(_Float16)f[k4*2+1][0]; h[5]=(_Float16)f[k4*2+1][1];
          h[6]=(_Float16)f[k4*2+1][2]; h[7]=(_Float16)f[k4*2+1][3];
          *(half8v*)(smem + (uint32_t)(u >> 6) * RSB + (uint32_t)(u & 63) * 16u) = h;
        }
      }
    }
    __syncthreads();
  }

  /* ---- merge the two t-halves (exact), then normalize + store ---- */
  float* mlb = (float*)(smem + MLOFF);
  if (g == 0) {
    mlb[th * 32 + qg * 16 + l15]      = mrun;
    mlb[64 + th * 32 + qg * 16 + l15] = lrun;
  }
  __syncthreads();
  const float mo = mlb[(1 - th) * 32 + qg * 16 + l15];
  const float lo = mlb[64 + (1 - th) * 32 + qg * 16 + l15];
  const float mfin = fmaxf(mrun, mo);
  const float sc_self = __expf(mrun - mfin);
  const float lfin = lrun * sc_self + lo * __expf(mo - mfin);
  float rs[4], inv[4];
#pragma unroll
  for (int r = 0; r < 4; ++r) {
    rs[r]  = __shfl(sc_self, 4 * g + r);
    inv[r] = 1.0f / __shfl(lfin, 4 * g + r);
  }
  if (th == 1) {
#pragma unroll
    for (int dt = 0; dt < NDT; ++dt) {
#pragma unroll
      for (int r = 0; r < 4; ++r) {
        const int qr = qg * 16 + 4 * g + r;
        *(float*)(smem + (uint32_t)qr * MRGS + (uint32_t)(dt * 16 + l15) * 4u) =
            acc[dt][r] * rs[r];
      }
    }
  }
  __syncthreads();
  if (th == 0) {
#pragma unroll
    for (int dt = 0; dt < NDT; ++dt) {
#pragma unroll
      for (int r = 0; r < 4; ++r) {
        const int qr = qg * 16 + 4 * g + r;
        const float o1 =
            *(const float*)(smem + (uint32_t)qr * MRGS + (uint32_t)(dt * 16 + l15) * 4u);
        const int q = qbase + qr;
        outb[(size_t)q * (2 * DD) + DD + dt * 16 + l15] =
            (acc[dt][r] * rs[r] + o1) * inv[r];
      }
    }
  }
}

extern "C" void kernel_launch(void* const* d_in, const int* in_sizes, int n_in,
                              void* d_out, int out_size, void* d_ws, size_t ws_size,
                              hipStream_t stream) {
  (void)in_sizes; (void)n_in; (void)out_size; (void)d_ws; (void)ws_size;
  const float* x = (const float*)d_in[0];
  const float* y = (const float*)d_in[1];
  float* out = (float*)d_out;
  static_assert(LDS_BYTES <= 80 * 1024, "need 2 blocks/CU");
  hipFuncSetAttribute((const void*)attn_fused,
                      hipFuncAttributeMaxDynamicSharedMemorySize, LDS_BYTES);
  hipLaunchKernelGGL(attn_fused, dim3((SXX / QBLK) * NB), dim3(256), LDS_BYTES,
                     stream, x, y, out);
}

// Round 4
// 121.096 us; speedup vs baseline: 1.9073x; 1.9073x over previous
//
#include <hip/hip_runtime.h>
#include <stdint.h>

typedef _Float16 half4v __attribute__((ext_vector_type(4)));
typedef _Float16 half8v __attribute__((ext_vector_type(8)));
typedef float    f32x4  __attribute__((ext_vector_type(4)));
typedef __attribute__((address_space(3))) void       lds_void;
typedef const __attribute__((address_space(1))) void g_void;

#define NB 8
#define SXX 2048
#define DD 512
#define QBLK 64
#define TBLK 64
#define NDT 32                 /* D/16 d-tiles */
#define NITER 32               /* 2048 / TBLK */

/* y tile: row-major fp16, padded rows 520 f16 = 1040 B (bank-rotate 4/row).
   1040 = 65*16 so global_load_lds (1 row = one 1KB wave-instr, contiguous)
   is compatible with the pad. */
#define RSB 1040u
#define BUFSZ (64u * RSB)      /* 66560 */
#define MRGS 2064u             /* merge row stride (516 f32) */
#define MLOFF (2u * BUFSZ)     /* 133120 */
#define LDS_BYTES 134144
#define YH_BYTES (8ull * 2048ull * 512ull * 2ull)   /* 16 MiB fp16 y */

__global__ __launch_bounds__(256)
void convert_y(const float* __restrict__ y, _Float16* __restrict__ yh) {
  const int i = (blockIdx.x * 256 + threadIdx.x) * 8;
  f32x4 f0 = *(const f32x4*)(y + i);
  f32x4 f1 = *(const f32x4*)(y + i + 4);
  half8v h;
  h[0]=(_Float16)f0[0]; h[1]=(_Float16)f0[1]; h[2]=(_Float16)f0[2]; h[3]=(_Float16)f0[3];
  h[4]=(_Float16)f1[0]; h[5]=(_Float16)f1[1]; h[6]=(_Float16)f1[2]; h[7]=(_Float16)f1[3];
  *(half8v*)(yh + i) = h;
}

template <bool USE_WS>
__global__ __launch_bounds__(512, 2)
void attn_fused(const float* __restrict__ x, const float* __restrict__ y,
                const _Float16* __restrict__ yh, float* __restrict__ out) {
  extern __shared__ char smem[];
  const int bid   = blockIdx.x;
  const int b     = bid & 7;      /* one batch per XCD -> y batch L2-resident */
  const int qtile = bid >> 3;
  const int tid   = threadIdx.x;
  const int wave  = tid >> 6;     /* 0..7 */
  const int lane  = tid & 63;
  const int l15   = lane & 15;
  const int g     = lane >> 4;
  const int qw    = wave & 3;     /* q-subtile (16 rows) */
  const int th    = wave >> 2;    /* t-half (32 t per tile) */

  const float*    xb  = x  + (size_t)b * SXX * DD;
  const float*    yb  = y  + (size_t)b * SXX * DD;
  const _Float16* yhb = USE_WS ? (yh + (size_t)b * SXX * DD) : nullptr;
  float* outb = out + (size_t)b * SXX * (2 * DD);
  const int qbase = qtile * QBLK;

  char* cbuf = smem;
  char* nbuf = smem + BUFSZ;

  /* async-stage tile 0 while we do the x-copy and Q loads */
  if (USE_WS) {
#pragma unroll
    for (int i = 0; i < 8; ++i) {
      const int row = wave * 8 + i;
      g_void*   gp = (g_void*)(yhb + row * DD + lane * 8);
      lds_void* lp = (lds_void*)(cbuf + (uint32_t)row * RSB);
      __builtin_amdgcn_global_load_lds(gp, lp, 16, 0, 0);
    }
  }

  /* ---- out[:, :512] = x (exact fp32 copy) ---- */
  {
    const f32x4* src = (const f32x4*)(xb + (size_t)qbase * DD);
    for (int i = tid; i < QBLK * (DD / 4); i += 512) {
      f32x4 v = src[i];
      const int row = i >> 7;
      const int c4  = i & 127;
      *(f32x4*)(outb + (size_t)(qbase + row) * (2 * DD) + c4 * 4) = v;
    }
  }

  /* ---- Q fragments (fp16), B-operand of 16x16x32:
     lane holds col q = qbase+16*qw+l15, elems d = 32c + 8g + j ---- */
  const int qrow = qbase + qw * 16 + l15;
  half8v bq[16];
  {
    const float* xr = xb + (size_t)qrow * DD;
#pragma unroll
    for (int c = 0; c < 16; ++c) {
      const int d0 = c * 32 + g * 8;
      f32x4 f0 = *(const f32x4*)(xr + d0);
      f32x4 f1 = *(const f32x4*)(xr + d0 + 4);
      half8v h;
      h[0] = (_Float16)f0[0]; h[1] = (_Float16)f0[1];
      h[2] = (_Float16)f0[2]; h[3] = (_Float16)f0[3];
      h[4] = (_Float16)f1[0]; h[5] = (_Float16)f1[1];
      h[6] = (_Float16)f1[2]; h[7] = (_Float16)f1[3];
      bq[c] = h;
    }
  }

  if (!USE_WS) {
    /* fallback: in-kernel convert-stage of tile 0 */
#pragma unroll
    for (int kb = 0; kb < 2; ++kb) {
      f32x4 f[8];
#pragma unroll
      for (int k4 = 0; k4 < 4; ++k4) {
        const int u = tid + (kb * 4 + k4) * 512;
        const float* p = yb + (u >> 6) * DD + (u & 63) * 8;
        f[k4 * 2]     = *(const f32x4*)(p);
        f[k4 * 2 + 1] = *(const f32x4*)(p + 4);
      }
#pragma unroll
      for (int k4 = 0; k4 < 4; ++k4) {
        const int u = tid + (kb * 4 + k4) * 512;
        half8v h;
        h[0]=(_Float16)f[k4*2][0]; h[1]=(_Float16)f[k4*2][1];
        h[2]=(_Float16)f[k4*2][2]; h[3]=(_Float16)f[k4*2][3];
        h[4]=(_Float16)f[k4*2+1][0]; h[5]=(_Float16)f[k4*2+1][1];
        h[6]=(_Float16)f[k4*2+1][2]; h[7]=(_Float16)f[k4*2+1][3];
        *(half8v*)(cbuf + (uint32_t)(u >> 6) * RSB + (uint32_t)(u & 63) * 16u) = h;
      }
    }
  }

  f32x4 acc[NDT];
#pragma unroll
  for (int i = 0; i < NDT; ++i) acc[i] = (f32x4){0.f, 0.f, 0.f, 0.f};
  float mrun = -3.0e38f;
  float lrun = 0.0f;

  __syncthreads();

  for (int it = 0; it < NITER; ++it) {
    const uint32_t cb = (uint32_t)(cbuf - smem);

    /* async-issue next tile's staging before compute (USE_WS path) */
    if (USE_WS && it + 1 < NITER) {
      const _Float16* src = yhb + (size_t)(it + 1) * TBLK * DD;
#pragma unroll
      for (int i = 0; i < 8; ++i) {
        const int row = wave * 8 + i;
        g_void*   gp = (g_void*)(src + row * DD + lane * 8);
        lds_void* lp = (lds_void*)(nbuf + (uint32_t)row * RSB);
        __builtin_amdgcn_global_load_lds(gp, lp, 16, 0, 0);
      }
    }

    /* ---- QK^T swapped: S^T = mfma(A=y, B=x) on this wave's 32 t-rows.
       C: lane holds q = l15 (col), t-row = 32*th + 16*tt + 4g + r. ---- */
    f32x4 st[2];
    st[0] = (f32x4){0.f, 0.f, 0.f, 0.f};
    st[1] = (f32x4){0.f, 0.f, 0.f, 0.f};
#pragma unroll
    for (int c = 0; c < 16; ++c) {
      const uint32_t db = cb + 64u * (uint32_t)c + 16u * (uint32_t)g;
#pragma unroll
      for (int tt = 0; tt < 2; ++tt) {
        const half8v af =
            *(const half8v*)(smem + (uint32_t)(th * 32 + tt * 16 + l15) * RSB + db);
        st[tt] = __builtin_amdgcn_mfma_f32_16x16x32_f16(af, bq[c], st[tt], 0, 0, 0);
      }
    }

    /* ---- online softmax over this wave's 32 t's, per q = l15 ---- */
    float tmax = -3.0e38f;
#pragma unroll
    for (int tt = 0; tt < 2; ++tt) {
#pragma unroll
      for (int r = 0; r < 4; ++r) tmax = fmaxf(tmax, st[tt][r]);
    }
    tmax = fmaxf(tmax, __shfl_xor(tmax, 16));
    tmax = fmaxf(tmax, __shfl_xor(tmax, 32));
    const float mnew = fmaxf(mrun, tmax);
    const bool  need = (mnew > mrun);
    float pvv[8];
    float rsum = 0.f;
#pragma unroll
    for (int tt = 0; tt < 2; ++tt) {
#pragma unroll
      for (int r = 0; r < 4; ++r) {
        const float e = __expf(st[tt][r] - mnew);
        pvv[tt * 4 + r] = e;
        rsum += e;
      }
    }
    rsum += __shfl_xor(rsum, 16);
    rsum += __shfl_xor(rsum, 32);
    const float scale = __expf(mrun - mnew);
    lrun = lrun * scale + rsum;
    mrun = mnew;

    if (__any(need)) {
      float rs[4];
#pragma unroll
      for (int r = 0; r < 4; ++r) rs[r] = __shfl(scale, 4 * g + r);
#pragma unroll
      for (int dt = 0; dt < NDT; ++dt) {
        acc[dt][0] *= rs[0]; acc[dt][1] *= rs[1];
        acc[dt][2] *= rs[2]; acc[dt][3] *= rs[3];
      }
    }

    /* ---- P A-fragment (16x16x32, K = this wave's 32 t's) ---- */
    half8v pa8;
#pragma unroll
    for (int j = 0; j < 8; ++j) pa8[j] = (_Float16)pvv[j];

    /* ---- PV: V B-fragments via positional tr-read, 2-ahead pipelined ---- */
    {
      const uint32_t rb = cb + (uint32_t)(th * 32 + 4 * g + (l15 >> 2)) * RSB +
                          (uint32_t)(l15 & 3) * 8u;
      half4v trv[3][2];
#pragma unroll
      for (int dt = 0; dt < NDT + 2; ++dt) {
        if (dt < NDT) {
          const uint32_t a = rb + (uint32_t)dt * 32u;
          const int s = dt % 3;
          asm volatile("ds_read_b64_tr_b16 %0, %1" : "=v"(trv[s][0]) : "v"(a));
          asm volatile("ds_read_b64_tr_b16 %0, %1" : "=v"(trv[s][1]) : "v"(a + 16u * RSB));
        }
        if (dt >= 2) {
          if (dt < NDT) {
            asm volatile("s_waitcnt lgkmcnt(4)" ::: "memory");
          } else if (dt == NDT) {
            asm volatile("s_waitcnt lgkmcnt(2)" ::: "memory");
          } else {
            asm volatile("s_waitcnt lgkmcnt(0)" ::: "memory");
          }
          __builtin_amdgcn_sched_barrier(0);
          const int dd = dt - 2;
          const int s = dd % 3;
          const half8v b8 = __builtin_shufflevector(trv[s][0], trv[s][1],
                                                    0, 1, 2, 3, 4, 5, 6, 7);
          acc[dd] = __builtin_amdgcn_mfma_f32_16x16x32_f16(pa8, b8, acc[dd], 0, 0, 0);
        }
      }
    }

    /* fallback: synchronous convert-stage of tile it+1 into nbuf */
    if (!USE_WS && it + 1 < NITER) {
      const float* ybt = yb + (size_t)(it + 1) * TBLK * DD;
#pragma unroll
      for (int kb = 0; kb < 2; ++kb) {
        f32x4 f[8];
#pragma unroll
        for (int k4 = 0; k4 < 4; ++k4) {
          const int u = tid + (kb * 4 + k4) * 512;
          const float* p = ybt + (u >> 6) * DD + (u & 63) * 8;
          f[k4 * 2]     = *(const f32x4*)(p);
          f[k4 * 2 + 1] = *(const f32x4*)(p + 4);
        }
#pragma unroll
        for (int k4 = 0; k4 < 4; ++k4) {
          const int u = tid + (kb * 4 + k4) * 512;
          half8v h;
          h[0]=(_Float16)f[k4*2][0]; h[1]=(_Float16)f[k4*2][1];
          h[2]=(_Float16)f[k4*2][2]; h[3]=(_Float16)f[k4*2][3];
          h[4]=(_Float16)f[k4*2+1][0]; h[5]=(_Float16)f[k4*2+1][1];
          h[6]=(_Float16)f[k4*2+1][2]; h[7]=(_Float16)f[k4*2+1][3];
          *(half8v*)(nbuf + (uint32_t)(u >> 6) * RSB + (uint32_t)(u & 63) * 16u) = h;
        }
      }
    }

    __syncthreads();
    char* t = cbuf; cbuf = nbuf; nbuf = t;
  }

  /* ---- merge the two t-halves (exact), then normalize + store ---- */
  float* mlb = (float*)(smem + MLOFF);
  if (g == 0) {
    mlb[th * 64 + qw * 16 + l15]       = mrun;
    mlb[128 + th * 64 + qw * 16 + l15] = lrun;
  }
  __syncthreads();
  const float mo = mlb[(1 - th) * 64 + qw * 16 + l15];
  const float lo = mlb[128 + (1 - th) * 64 + qw * 16 + l15];
  const float mfin = fmaxf(mrun, mo);
  const float sc_self = __expf(mrun - mfin);
  const float lfin = lrun * sc_self + lo * __expf(mo - mfin);
  float rs[4], inv[4];
#pragma unroll
  for (int r = 0; r < 4; ++r) {
    rs[r]  = __shfl(sc_self, 4 * g + r);
    inv[r] = 1.0f / __shfl(lfin, 4 * g + r);
  }
  if (th == 1) {
#pragma unroll
    for (int dt = 0; dt < NDT; ++dt) {
#pragma unroll
      for (int r = 0; r < 4; ++r) {
        const int qr = qw * 16 + 4 * g + r;
        *(float*)(smem + (uint32_t)qr * MRGS + (uint32_t)(dt * 16 + l15) * 4u) =
            acc[dt][r] * rs[r];
      }
    }
  }
  __syncthreads();
  if (th == 0) {
#pragma unroll
    for (int dt = 0; dt < NDT; ++dt) {
#pragma unroll
      for (int r = 0; r < 4; ++r) {
        const int qr = qw * 16 + 4 * g + r;
        const float o1 =
            *(const float*)(smem + (uint32_t)qr * MRGS + (uint32_t)(dt * 16 + l15) * 4u);
        const int q = qbase + qr;
        outb[(size_t)q * (2 * DD) + DD + dt * 16 + l15] =
            (acc[dt][r] * rs[r] + o1) * inv[r];
      }
    }
  }
}

extern "C" void kernel_launch(void* const* d_in, const int* in_sizes, int n_in,
                              void* d_out, int out_size, void* d_ws, size_t ws_size,
                              hipStream_t stream) {
  (void)in_sizes; (void)n_in; (void)out_size;
  const float* x = (const float*)d_in[0];
  const float* y = (const float*)d_in[1];
  float* out = (float*)d_out;
  static_assert(LDS_BYTES <= 160 * 1024, "LDS over budget");
  const bool use_ws = (ws_size >= YH_BYTES);
  if (use_ws) {
    _Float16* yh = (_Float16*)d_ws;
    hipLaunchKernelGGL(convert_y, dim3(4096), dim3(256), 0, stream, y, yh);
    hipFuncSetAttribute((const void*)attn_fused<true>,
                        hipFuncAttributeMaxDynamicSharedMemorySize, LDS_BYTES);
    hipLaunchKernelGGL((attn_fused<true>), dim3((SXX / QBLK) * NB), dim3(512),
                       LDS_BYTES, stream, x, y, yh, out);
  } else {
    hipFuncSetAttribute((const void*)attn_fused<false>,
                        hipFuncAttributeMaxDynamicSharedMemorySize, LDS_BYTES);
    hipLaunchKernelGGL((attn_fused<false>), dim3((SXX / QBLK) * NB), dim3(512),
                       LDS_BYTES, stream, x, y, nullptr, out);
  }
}

// Round 7
// 116.349 us; speedup vs baseline: 1.9851x; 1.0408x over previous
//
#include <hip/hip_runtime.h>
#include <stdint.h>

typedef _Float16 half4v __attribute__((ext_vector_type(4)));
typedef _Float16 half8v __attribute__((ext_vector_type(8)));
typedef float    f32x4  __attribute__((ext_vector_type(4)));
typedef __attribute__((address_space(3))) void       lds_void;
typedef const __attribute__((address_space(1))) void g_void;

#define NB 8
#define SXX 2048
#define DD 512
#define QBLK 64
#define TBLK 64
#define NITER 32

/* y tile: row-major fp16, padded rows 520 f16 = 1040 B (bank-rotate 4/row). */
#define RSB 1040u
#define BUFSZ (64u * RSB)          /* 66560 */
#define POFF  (2u * BUFSZ)         /* 133120: P[64 q][64 t] fp16, row 136 B */
#define PR    136u
#define SCOFF (POFF + 64u * PR)    /* 141824: per-q scale f32[64] */
#define LIOFF (SCOFF + 256u)       /* 142080: per-q 1/l f32[64] */
#define LDS_BYTES 142336
#define YH_BYTES (8ull * 2048ull * 512ull * 2ull)   /* 16 MiB fp16 y */

__global__ __launch_bounds__(256)
void convert_y(const float* __restrict__ y, _Float16* __restrict__ yh) {
  const int i = (blockIdx.x * 256 + threadIdx.x) * 8;
  f32x4 f0 = *(const f32x4*)(y + i);
  f32x4 f1 = *(const f32x4*)(y + i + 4);
  half8v h;
  h[0]=(_Float16)f0[0]; h[1]=(_Float16)f0[1]; h[2]=(_Float16)f0[2]; h[3]=(_Float16)f0[3];
  h[4]=(_Float16)f1[0]; h[5]=(_Float16)f1[1]; h[6]=(_Float16)f1[2]; h[7]=(_Float16)f1[3];
  *(half8v*)(yh + i) = h;
}

template <bool USE_WS>
__global__ __launch_bounds__(512, 2)
void attn_fused(const float* __restrict__ x, const float* __restrict__ y,
                const _Float16* __restrict__ yh, float* __restrict__ out) {
  extern __shared__ char smem[];
  const int bid   = blockIdx.x;
  const int b     = bid & 7;      /* one batch per XCD -> yh batch L2-resident */
  const int qtile = bid >> 3;
  const int tid   = threadIdx.x;
  const int w     = tid >> 6;     /* 0..7: QK wave (w<4, 16q each) / PV d-slice */
  const int lane  = tid & 63;
  const int l15   = lane & 15;
  const int g     = lane >> 4;

  const float*    xb  = x + (size_t)b * SXX * DD;
  const float*    yb  = y + (size_t)b * SXX * DD;
  const _Float16* yhb = USE_WS ? (yh + (size_t)b * SXX * DD) : nullptr;
  float* outb = out + (size_t)b * SXX * (2 * DD);
  const int qbase = qtile * QBLK;

  /* async-stage tile 0 */
  if (USE_WS) {
#pragma unroll
    for (int i = 0; i < 8; ++i) {
      const int row = w * 8 + i;
      __builtin_amdgcn_global_load_lds((g_void*)(yhb + row * DD + lane * 8),
                                       (lds_void*)(smem + (uint32_t)row * RSB), 16, 0, 0);
    }
  }

  /* ---- out[:, :512] = x (exact fp32 copy) ---- */
  {
    const f32x4* src = (const f32x4*)(xb + (size_t)qbase * DD);
    for (int i = tid; i < QBLK * (DD / 4); i += 512) {
      f32x4 v = src[i];
      *(f32x4*)(outb + (size_t)(qbase + (i >> 7)) * (2 * DD) + (i & 127) * 4) = v;
    }
  }

  /* ---- Q fragments (fp16), B-operand of 16x16x32 (waves 0..3 only) ---- */
  half8v bq[16];
  if (w < 4) {
    const float* xr = xb + (size_t)(qbase + w * 16 + l15) * DD;
#pragma unroll
    for (int c = 0; c < 16; ++c) {
      const int d0 = c * 32 + g * 8;
      f32x4 f0 = *(const f32x4*)(xr + d0);
      f32x4 f1 = *(const f32x4*)(xr + d0 + 4);
      half8v h;
      h[0] = (_Float16)f0[0]; h[1] = (_Float16)f0[1];
      h[2] = (_Float16)f0[2]; h[3] = (_Float16)f0[3];
      h[4] = (_Float16)f1[0]; h[5] = (_Float16)f1[1];
      h[6] = (_Float16)f1[2]; h[7] = (_Float16)f1[3];
      bq[c] = h;
    }
  }

  if (!USE_WS) {
#pragma unroll
    for (int k = 0; k < 8; ++k) {
      const int u = tid + k * 512;
      const int t = u >> 6, c8 = u & 63;
      const float* p = yb + t * DD + c8 * 8;
      f32x4 f0 = *(const f32x4*)p, f1 = *(const f32x4*)(p + 4);
      half8v h;
      h[0]=(_Float16)f0[0]; h[1]=(_Float16)f0[1]; h[2]=(_Float16)f0[2]; h[3]=(_Float16)f0[3];
      h[4]=(_Float16)f1[0]; h[5]=(_Float16)f1[1]; h[6]=(_Float16)f1[2]; h[7]=(_Float16)f1[3];
      *(half8v*)(smem + (uint32_t)t * RSB + (uint32_t)c8 * 16u) = h;
    }
  }

  f32x4 acc[4][4];   /* [qq][dtl]: a[qbase+qq*16+4g+r][w*64+dtl*16+l15] */
#pragma unroll
  for (int i = 0; i < 4; ++i)
#pragma unroll
    for (int j = 0; j < 4; ++j) acc[i][j] = (f32x4){0.f, 0.f, 0.f, 0.f};
  float mrun = -3.0e38f, lrun = 0.0f;

  __syncthreads();

  for (int it = 0; it < NITER; ++it) {
    const uint32_t cb  = (uint32_t)(it & 1) * BUFSZ;
    const uint32_t nb2 = cb ^ BUFSZ;

    /* async-issue next tile into the other buffer */
    if (USE_WS && it + 1 < NITER) {
      const _Float16* src = yhb + (size_t)(it + 1) * TBLK * DD;
#pragma unroll
      for (int i = 0; i < 8; ++i) {
        const int row = w * 8 + i;
        __builtin_amdgcn_global_load_lds((g_void*)(src + row * DD + lane * 8),
                                         (lds_void*)(smem + nb2 + (uint32_t)row * RSB), 16, 0, 0);
      }
    }

    if (w < 4) {
      /* ---- QK^T swapped, full 64 t per wave:
         C: lane holds q = l15 (col), t = 16tt + 4g + r (row). ---- */
      f32x4 st[4];
#pragma unroll
      for (int tt = 0; tt < 4; ++tt) st[tt] = (f32x4){0.f, 0.f, 0.f, 0.f};
#pragma unroll
      for (int c = 0; c < 16; ++c) {
        const uint32_t db = cb + 64u * (uint32_t)c + 16u * (uint32_t)g;
#pragma unroll
        for (int tt = 0; tt < 4; ++tt) {
          const half8v af = *(const half8v*)(smem + (uint32_t)(tt * 16 + l15) * RSB + db);
          st[tt] = __builtin_amdgcn_mfma_f32_16x16x32_f16(af, bq[c], st[tt], 0, 0, 0);
        }
      }

      /* ---- online softmax over t, per q = l15 (replicated over 4 groups) */
      float tmax = -3.0e38f;
#pragma unroll
      for (int tt = 0; tt < 4; ++tt)
#pragma unroll
        for (int r = 0; r < 4; ++r) tmax = fmaxf(tmax, st[tt][r]);
      tmax = fmaxf(tmax, __shfl_xor(tmax, 16));
      tmax = fmaxf(tmax, __shfl_xor(tmax, 32));
      const float mnew = fmaxf(mrun, tmax);
      float pvv[16];
      float rsum = 0.f;
#pragma unroll
      for (int tt = 0; tt < 4; ++tt)
#pragma unroll
        for (int r = 0; r < 4; ++r) {
          const float e = __expf(st[tt][r] - mnew);
          pvv[tt * 4 + r] = e;
          rsum += e;
        }
      rsum += __shfl_xor(rsum, 16);
      rsum += __shfl_xor(rsum, 32);
      const float scale = __expf(mrun - mnew);
      lrun = lrun * scale + rsum;
      mrun = mnew;

      /* write P[q = w*16+l15][t = 16tt+4g+r] (fp16) and per-q scale */
#pragma unroll
      for (int tt = 0; tt < 4; ++tt) {
        half4v hv;
        hv[0] = (_Float16)pvv[tt * 4 + 0]; hv[1] = (_Float16)pvv[tt * 4 + 1];
        hv[2] = (_Float16)pvv[tt * 4 + 2]; hv[3] = (_Float16)pvv[tt * 4 + 3];
        *(half4v*)(smem + POFF + (uint32_t)(w * 16 + l15) * PR +
                   (uint32_t)tt * 32u + (uint32_t)g * 8u) = hv;
      }
      if (g == 0) ((float*)(smem + SCOFF))[w * 16 + l15] = scale;
    }

    if (!USE_WS && it + 1 < NITER) {
      const float* ybt = yb + (size_t)(it + 1) * TBLK * DD;
#pragma unroll
      for (int k = 0; k < 8; ++k) {
        const int u = tid + k * 512;
        const int t = u >> 6, c8 = u & 63;
        const float* p = ybt + t * DD + c8 * 8;
        f32x4 f0 = *(const f32x4*)p, f1 = *(const f32x4*)(p + 4);
        half8v h;
        h[0]=(_Float16)f0[0]; h[1]=(_Float16)f0[1]; h[2]=(_Float16)f0[2]; h[3]=(_Float16)f0[3];
        h[4]=(_Float16)f1[0]; h[5]=(_Float16)f1[1]; h[6]=(_Float16)f1[2]; h[7]=(_Float16)f1[3];
        *(half8v*)(smem + nb2 + (uint32_t)t * RSB + (uint32_t)c8 * 16u) = h;
      }
    }

    __syncthreads();   /* B1: P/scales visible, staging drained */

    /* ---- PV: all 8 waves, disjoint 64-d slices ---- */
    {
      /* unconditional rescale (scale==1 when no new max) */
#pragma unroll
      for (int qq = 0; qq < 4; ++qq) {
        const f32x4 s4 = *(const f32x4*)(smem + SCOFF + (uint32_t)(qq * 16 + 4 * g) * 4u);
#pragma unroll
        for (int dtl = 0; dtl < 4; ++dtl) {
          acc[qq][dtl][0] *= s4[0]; acc[qq][dtl][1] *= s4[1];
          acc[qq][dtl][2] *= s4[2]; acc[qq][dtl][3] *= s4[3];
        }
      }
      __builtin_amdgcn_sched_barrier(0);

      /* batch-issue ALL PV LDS reads, then one full wait */
      half4v palo[4][2], pahi[4][2];
      const uint32_t pb = POFF + (uint32_t)l15 * PR + (uint32_t)g * 8u;
#pragma unroll
      for (int qq = 0; qq < 4; ++qq)
#pragma unroll
        for (int ch = 0; ch < 2; ++ch) {
          const uint32_t a = pb + (uint32_t)qq * (16u * PR) + (uint32_t)ch * 64u;
          asm volatile("ds_read_b64 %0, %1" : "=v"(palo[qq][ch]) : "v"(a));
          asm volatile("ds_read_b64 %0, %1" : "=v"(pahi[qq][ch]) : "v"(a + 32u));
        }
      half4v blo[8], bhi[8];
      const uint32_t tb = cb + (uint32_t)(4 * g + (l15 >> 2)) * RSB +
                          (uint32_t)(l15 & 3) * 8u + (uint32_t)w * 128u;
#pragma unroll
      for (int fr = 0; fr < 8; ++fr) {
        const uint32_t a = tb + (uint32_t)(fr >> 2) * (32u * RSB) + (uint32_t)(fr & 3) * 32u;
        asm volatile("ds_read_b64_tr_b16 %0, %1" : "=v"(blo[fr]) : "v"(a));
        asm volatile("ds_read_b64_tr_b16 %0, %1" : "=v"(bhi[fr]) : "v"(a + 16u * RSB));
      }
      asm volatile("s_waitcnt lgkmcnt(0)" ::: "memory");
      __builtin_amdgcn_sched_barrier(0);

#pragma unroll
      for (int fr = 0; fr < 8; ++fr) {
        const half8v b8 = __builtin_shufflevector(blo[fr], bhi[fr], 0, 1, 2, 3, 4, 5, 6, 7);
        const int ch = fr >> 2, dtl = fr & 3;
#pragma unroll
        for (int qq = 0; qq < 4; ++qq) {
          const half8v pa = __builtin_shufflevector(palo[qq][ch], pahi[qq][ch],
                                                    0, 1, 2, 3, 4, 5, 6, 7);
          acc[qq][dtl] = __builtin_amdgcn_mfma_f32_16x16x32_f16(pa, b8, acc[qq][dtl], 0, 0, 0);
        }
      }
    }
    __syncthreads();   /* B2: PV reads of P/cbuf done */
  }

  /* ---- epilogue: 1/l then store a into out[:, 512:] ---- */
  if (w < 4 && g == 0) ((float*)(smem + LIOFF))[w * 16 + l15] = 1.0f / lrun;
  __syncthreads();
#pragma unroll
  for (int qq = 0; qq < 4; ++qq) {
    const f32x4 iv = *(const f32x4*)(smem + LIOFF + (uint32_t)(qq * 16 + 4 * g) * 4u);
#pragma unroll
    for (int dtl = 0; dtl < 4; ++dtl) {
#pragma unroll
      for (int r = 0; r < 4; ++r) {
        const int q = qbase + qq * 16 + 4 * g + r;
        outb[(size_t)q * (2 * DD) + DD + w * 64 + dtl * 16 + l15] = acc[qq][dtl][r] * iv[r];
      }
    }
  }
}

extern "C" void kernel_launch(void* const* d_in, const int* in_sizes, int n_in,
                              void* d_out, int out_size, void* d_ws, size_t ws_size,
                              hipStream_t stream) {
  (void)in_sizes; (void)n_in; (void)out_size;
  const float* x = (const float*)d_in[0];
  const float* y = (const float*)d_in[1];
  float* out = (float*)d_out;
  static_assert(LDS_BYTES <= 160 * 1024, "LDS over budget");
  const bool use_ws = (ws_size >= YH_BYTES);
  if (use_ws) {
    _Float16* yh = (_Float16*)d_ws;
    hipLaunchKernelGGL(convert_y, dim3(4096), dim3(256), 0, stream, y, yh);
    hipFuncSetAttribute((const void*)attn_fused<true>,
                        hipFuncAttributeMaxDynamicSharedMemorySize, LDS_BYTES);
    hipLaunchKernelGGL((attn_fused<true>), dim3((SXX / QBLK) * NB), dim3(512),
                       LDS_BYTES, stream, x, y, yh, out);
  } else {
    hipFuncSetAttribute((const void*)attn_fused<false>,
                        hipFuncAttributeMaxDynamicSharedMemorySize, LDS_BYTES);
    hipLaunchKernelGGL((attn_fused<false>), dim3((SXX / QBLK) * NB), dim3(512),
                       LDS_BYTES, stream, x, y, nullptr, out);
  }
}

// Round 8
// 115.588 us; speedup vs baseline: 1.9982x; 1.0066x over previous
//
#include <hip/hip_runtime.h>
#include <stdint.h>

typedef _Float16 half4v __attribute__((ext_vector_type(4)));
typedef _Float16 half8v __attribute__((ext_vector_type(8)));
typedef float    f32x4  __attribute__((ext_vector_type(4)));
typedef __attribute__((address_space(3))) void       lds_void;
typedef const __attribute__((address_space(1))) void g_void;

#define NB 8
#define SXX 2048
#define DD 512
#define QBLK 64
#define TBLK 64
#define NITER 32

/* y tile: row-major fp16, padded rows 520 f16 = 1040 B (bank-rotate 4/row). */
#define RSB 1040u
#define BUFSZ (64u * RSB)          /* 66560 */
#define POFF  (2u * BUFSZ)         /* 133120: P[64 q][64 t] fp16, row 136 B */
#define PR    136u
#define SCOFF (POFF + 64u * PR)    /* 141824: per-q scale f32[64] */
#define TMOFF (SCOFF + 256u)       /* 142080: per-(half,q) tile-max f32[2][64] */
#define LOFF  (TMOFF + 512u)       /* 142592: per-(half,q) l f32[2][64] */
#define LDS_BYTES 143104
#define YH_BYTES (8ull * 2048ull * 512ull * 2ull)   /* 16 MiB fp16 y */

__global__ __launch_bounds__(256)
void convert_y(const float* __restrict__ y, _Float16* __restrict__ yh) {
  const int i = (blockIdx.x * 256 + threadIdx.x) * 8;
  f32x4 f0 = *(const f32x4*)(y + i);
  f32x4 f1 = *(const f32x4*)(y + i + 4);
  half8v h;
  h[0]=(_Float16)f0[0]; h[1]=(_Float16)f0[1]; h[2]=(_Float16)f0[2]; h[3]=(_Float16)f0[3];
  h[4]=(_Float16)f1[0]; h[5]=(_Float16)f1[1]; h[6]=(_Float16)f1[2]; h[7]=(_Float16)f1[3];
  *(half8v*)(yh + i) = h;
}

template <bool USE_WS>
__global__ __launch_bounds__(512, 2)
void attn_fused(const float* __restrict__ x, const float* __restrict__ y,
                const _Float16* __restrict__ yh, float* __restrict__ out) {
  extern __shared__ char smem[];
  const int bid   = blockIdx.x;
  const int b     = bid & 7;      /* one batch per XCD -> yh batch L2-resident */
  const int qtile = bid >> 3;
  const int tid   = threadIdx.x;
  const int w     = tid >> 6;     /* 0..7 */
  const int lane  = tid & 63;
  const int l15   = lane & 15;
  const int g     = lane >> 4;
  const int qw    = w & 3;        /* q-subtile (16 rows) for QK */
  const int th    = w >> 2;       /* t-half (32 t) for QK */

  const float*    xb  = x + (size_t)b * SXX * DD;
  const float*    yb  = y + (size_t)b * SXX * DD;
  const _Float16* yhb = USE_WS ? (yh + (size_t)b * SXX * DD) : nullptr;
  float* outb = out + (size_t)b * SXX * (2 * DD);
  const int qbase = qtile * QBLK;

  /* async-stage tile 0 */
  if (USE_WS) {
#pragma unroll
    for (int i = 0; i < 8; ++i) {
      const int row = w * 8 + i;
      __builtin_amdgcn_global_load_lds((g_void*)(yhb + row * DD + lane * 8),
                                       (lds_void*)(smem + (uint32_t)row * RSB), 16, 0, 0);
    }
  }

  /* ---- out[:, :512] = x (exact fp32 copy) ---- */
  {
    const f32x4* src = (const f32x4*)(xb + (size_t)qbase * DD);
    for (int i = tid; i < QBLK * (DD / 4); i += 512) {
      f32x4 v = src[i];
      *(f32x4*)(outb + (size_t)(qbase + (i >> 7)) * (2 * DD) + (i & 127) * 4) = v;
    }
  }

  /* ---- Q fragments (fp16), B-operand of 16x16x32, ALL waves:
     lane holds col q = qbase+16*qw+l15, elems d = 32c + 8g + j ---- */
  half8v bq[16];
  {
    const float* xr = xb + (size_t)(qbase + qw * 16 + l15) * DD;
#pragma unroll
    for (int c = 0; c < 16; ++c) {
      const int d0 = c * 32 + g * 8;
      f32x4 f0 = *(const f32x4*)(xr + d0);
      f32x4 f1 = *(const f32x4*)(xr + d0 + 4);
      half8v h;
      h[0] = (_Float16)f0[0]; h[1] = (_Float16)f0[1];
      h[2] = (_Float16)f0[2]; h[3] = (_Float16)f0[3];
      h[4] = (_Float16)f1[0]; h[5] = (_Float16)f1[1];
      h[6] = (_Float16)f1[2]; h[7] = (_Float16)f1[3];
      bq[c] = h;
    }
  }

  if (!USE_WS) {
#pragma unroll
    for (int k = 0; k < 8; ++k) {
      const int u = tid + k * 512;
      const int t = u >> 6, c8 = u & 63;
      const float* p = yb + t * DD + c8 * 8;
      f32x4 f0 = *(const f32x4*)p, f1 = *(const f32x4*)(p + 4);
      half8v h;
      h[0]=(_Float16)f0[0]; h[1]=(_Float16)f0[1]; h[2]=(_Float16)f0[2]; h[3]=(_Float16)f0[3];
      h[4]=(_Float16)f1[0]; h[5]=(_Float16)f1[1]; h[6]=(_Float16)f1[2]; h[7]=(_Float16)f1[3];
      *(half8v*)(smem + (uint32_t)t * RSB + (uint32_t)c8 * 16u) = h;
    }
  }

  f32x4 acc[4][4];   /* [qq][dtl]: a[qbase+qq*16+4g+r][w*64+dtl*16+l15] */
#pragma unroll
  for (int i = 0; i < 4; ++i)
#pragma unroll
    for (int j = 0; j < 4; ++j) acc[i][j] = (f32x4){0.f, 0.f, 0.f, 0.f};
  float mrun = -3.0e38f, lrun = 0.0f;

  __syncthreads();

  for (int it = 0; it < NITER; ++it) {
    const uint32_t cb  = (uint32_t)(it & 1) * BUFSZ;
    const uint32_t nb2 = cb ^ BUFSZ;

    /* async-issue next tile into the other buffer */
    if (USE_WS && it + 1 < NITER) {
      const _Float16* src = yhb + (size_t)(it + 1) * TBLK * DD;
#pragma unroll
      for (int i = 0; i < 8; ++i) {
        const int row = w * 8 + i;
        __builtin_amdgcn_global_load_lds((g_void*)(src + row * DD + lane * 8),
                                         (lds_void*)(smem + nb2 + (uint32_t)row * RSB), 16, 0, 0);
      }
    }

    /* ---- QK^T swapped, t-split: wave (qw,th) does 16q x 32t.
       C: lane holds q = l15 (col), t = th*32 + 16tt + 4g + r (row). ---- */
    f32x4 st[2];
    st[0] = (f32x4){0.f, 0.f, 0.f, 0.f};
    st[1] = (f32x4){0.f, 0.f, 0.f, 0.f};
#pragma unroll
    for (int c = 0; c < 16; ++c) {
      const uint32_t db = cb + 64u * (uint32_t)c + 16u * (uint32_t)g;
#pragma unroll
      for (int tt = 0; tt < 2; ++tt) {
        const half8v af =
            *(const half8v*)(smem + (uint32_t)(th * 32 + tt * 16 + l15) * RSB + db);
        st[tt] = __builtin_amdgcn_mfma_f32_16x16x32_f16(af, bq[c], st[tt], 0, 0, 0);
      }
    }

    /* ---- tile-max over this wave's 32 t, exchange with partner half ---- */
    float tmax = -3.0e38f;
#pragma unroll
    for (int tt = 0; tt < 2; ++tt)
#pragma unroll
      for (int r = 0; r < 4; ++r) tmax = fmaxf(tmax, st[tt][r]);
    tmax = fmaxf(tmax, __shfl_xor(tmax, 16));
    tmax = fmaxf(tmax, __shfl_xor(tmax, 32));
    if (g == 0) ((float*)(smem + TMOFF))[th * 64 + qw * 16 + l15] = tmax;
    __syncthreads();   /* B-mid: tile-maxes visible */
    const float tm0 = ((float*)(smem + TMOFF))[qw * 16 + l15];
    const float tm1 = ((float*)(smem + TMOFF))[64 + qw * 16 + l15];
    const float mnew = fmaxf(mrun, fmaxf(tm0, tm1));   /* common across partners */

    float pvv[8];
    float rsum = 0.f;
#pragma unroll
    for (int tt = 0; tt < 2; ++tt)
#pragma unroll
      for (int r = 0; r < 4; ++r) {
        const float e = __expf(st[tt][r] - mnew);
        pvv[tt * 4 + r] = e;
        rsum += e;
      }
    rsum += __shfl_xor(rsum, 16);
    rsum += __shfl_xor(rsum, 32);
    const float scale = __expf(mrun - mnew);   /* identical for both partners */
    lrun = lrun * scale + rsum;
    mrun = mnew;

    /* write P[q = qw*16+l15][t = th*32+16tt+4g+r] (fp16); scale once per q */
#pragma unroll
    for (int tt = 0; tt < 2; ++tt) {
      half4v hv;
      hv[0] = (_Float16)pvv[tt * 4 + 0]; hv[1] = (_Float16)pvv[tt * 4 + 1];
      hv[2] = (_Float16)pvv[tt * 4 + 2]; hv[3] = (_Float16)pvv[tt * 4 + 3];
      *(half4v*)(smem + POFF + (uint32_t)(qw * 16 + l15) * PR +
                 (uint32_t)(th * 64 + tt * 32) + (uint32_t)g * 8u) = hv;
    }
    if (th == 0 && g == 0) ((float*)(smem + SCOFF))[qw * 16 + l15] = scale;

    if (!USE_WS && it + 1 < NITER) {
      const float* ybt = yb + (size_t)(it + 1) * TBLK * DD;
#pragma unroll
      for (int k = 0; k < 8; ++k) {
        const int u = tid + k * 512;
        const int t = u >> 6, c8 = u & 63;
        const float* p = ybt + t * DD + c8 * 8;
        f32x4 f0 = *(const f32x4*)p, f1 = *(const f32x4*)(p + 4);
        half8v h;
        h[0]=(_Float16)f0[0]; h[1]=(_Float16)f0[1]; h[2]=(_Float16)f0[2]; h[3]=(_Float16)f0[3];
        h[4]=(_Float16)f1[0]; h[5]=(_Float16)f1[1]; h[6]=(_Float16)f1[2]; h[7]=(_Float16)f1[3];
        *(half8v*)(smem + nb2 + (uint32_t)t * RSB + (uint32_t)c8 * 16u) = h;
      }
    }

    __syncthreads();   /* B1: P/scale visible, staging of cbuf-next drained */

    /* ---- PV: all 8 waves, disjoint 64-d slices ---- */
    {
      /* unconditional rescale (scale==1 when no new max) */
#pragma unroll
      for (int qq = 0; qq < 4; ++qq) {
        const f32x4 s4 = *(const f32x4*)(smem + SCOFF + (uint32_t)(qq * 16 + 4 * g) * 4u);
#pragma unroll
        for (int dtl = 0; dtl < 4; ++dtl) {
          acc[qq][dtl][0] *= s4[0]; acc[qq][dtl][1] *= s4[1];
          acc[qq][dtl][2] *= s4[2]; acc[qq][dtl][3] *= s4[3];
        }
      }
      __builtin_amdgcn_sched_barrier(0);

      /* batch-issue ALL PV LDS reads, then one full wait */
      half4v palo[4][2], pahi[4][2];
      const uint32_t pb = POFF + (uint32_t)l15 * PR + (uint32_t)g * 8u;
#pragma unroll
      for (int qq = 0; qq < 4; ++qq)
#pragma unroll
        for (int ch = 0; ch < 2; ++ch) {
          const uint32_t a = pb + (uint32_t)qq * (16u * PR) + (uint32_t)ch * 64u;
          asm volatile("ds_read_b64 %0, %1" : "=v"(palo[qq][ch]) : "v"(a));
          asm volatile("ds_read_b64 %0, %1" : "=v"(pahi[qq][ch]) : "v"(a + 32u));
        }
      half4v blo[8], bhi[8];
      const uint32_t tb = cb + (uint32_t)(4 * g + (l15 >> 2)) * RSB +
                          (uint32_t)(l15 & 3) * 8u + (uint32_t)w * 128u;
#pragma unroll
      for (int fr = 0; fr < 8; ++fr) {
        const uint32_t a = tb + (uint32_t)(fr >> 2) * (32u * RSB) + (uint32_t)(fr & 3) * 32u;
        asm volatile("ds_read_b64_tr_b16 %0, %1" : "=v"(blo[fr]) : "v"(a));
        asm volatile("ds_read_b64_tr_b16 %0, %1" : "=v"(bhi[fr]) : "v"(a + 16u * RSB));
      }
      asm volatile("s_waitcnt lgkmcnt(0)" ::: "memory");
      __builtin_amdgcn_sched_barrier(0);

#pragma unroll
      for (int fr = 0; fr < 8; ++fr) {
        const half8v b8 = __builtin_shufflevector(blo[fr], bhi[fr], 0, 1, 2, 3, 4, 5, 6, 7);
        const int ch = fr >> 2, dtl = fr & 3;
#pragma unroll
        for (int qq = 0; qq < 4; ++qq) {
          const half8v pa = __builtin_shufflevector(palo[qq][ch], pahi[qq][ch],
                                                    0, 1, 2, 3, 4, 5, 6, 7);
          acc[qq][dtl] = __builtin_amdgcn_mfma_f32_16x16x32_f16(pa, b8, acc[qq][dtl], 0, 0, 0);
        }
      }
    }
    __syncthreads();   /* B2: PV reads of P/cbuf done */
  }

  /* ---- epilogue: l = l(th=0) + l(th=1), then store a into out[:, 512:] ---- */
  if (g == 0) ((float*)(smem + LOFF))[th * 64 + qw * 16 + l15] = lrun;
  __syncthreads();
#pragma unroll
  for (int qq = 0; qq < 4; ++qq) {
    const f32x4 l0 = *(const f32x4*)(smem + LOFF + (uint32_t)(qq * 16 + 4 * g) * 4u);
    const f32x4 l1 = *(const f32x4*)(smem + LOFF + 256u + (uint32_t)(qq * 16 + 4 * g) * 4u);
    f32x4 iv;
#pragma unroll
    for (int r = 0; r < 4; ++r) iv[r] = 1.0f / (l0[r] + l1[r]);
#pragma unroll
    for (int dtl = 0; dtl < 4; ++dtl) {
#pragma unroll
      for (int r = 0; r < 4; ++r) {
        const int q = qbase + qq * 16 + 4 * g + r;
        outb[(size_t)q * (2 * DD) + DD + w * 64 + dtl * 16 + l15] = acc[qq][dtl][r] * iv[r];
      }
    }
  }
}

extern "C" void kernel_launch(void* const* d_in, const int* in_sizes, int n_in,
                              void* d_out, int out_size, void* d_ws, size_t ws_size,
                              hipStream_t stream) {
  (void)in_sizes; (void)n_in; (void)out_size;
  const float* x = (const float*)d_in[0];
  const float* y = (const float*)d_in[1];
  float* out = (float*)d_out;
  static_assert(LDS_BYTES <= 160 * 1024, "LDS over budget");
  const bool use_ws = (ws_size >= YH_BYTES);
  if (use_ws) {
    _Float16* yh = (_Float16*)d_ws;
    hipLaunchKernelGGL(convert_y, dim3(4096), dim3(256), 0, stream, y, yh);
    hipFuncSetAttribute((const void*)attn_fused<true>,
                        hipFuncAttributeMaxDynamicSharedMemorySize, LDS_BYTES);
    hipLaunchKernelGGL((attn_fused<true>), dim3((SXX / QBLK) * NB), dim3(512),
                       LDS_BYTES, stream, x, y, yh, out);
  } else {
    hipFuncSetAttribute((const void*)attn_fused<false>,
                        hipFuncAttributeMaxDynamicSharedMemorySize, LDS_BYTES);
    hipLaunchKernelGGL((attn_fused<false>), dim3((SXX / QBLK) * NB), dim3(512),
                       LDS_BYTES, stream, x, y, nullptr, out);
  }
}